// Round 2
// baseline (283.433 us; speedup 1.0000x reference)
//
#include <hip/hip_runtime.h>

#define NROWS 2097152
#define W 16
#define TPB 256
#define BLOCKS 2048
#define STRIDE (BLOCKS * TPB)          // 524288 threads = exactly 32 waves/CU
#define NF4 (NROWS * 4)                // 8388608 float4 chunks per input
#define NITER (NF4 / STRIDE)           // 16 — divides exactly, no tail
#define UNROLL 4

// (max, first-index) argmax combine — matches jnp.argmax tie-break
__device__ __forceinline__ void argmax_combine(float& m, int& i, float mo, int io)
{
    if (mo > m || (mo == m && io < i)) { m = mo; i = io; }
}

__global__ __launch_bounds__(TPB) void cel_weight_kernel(
    const float* __restrict__ predict,
    const float* __restrict__ target,
    const float* __restrict__ penalty,
    float* __restrict__ out)
{
    __shared__ float s_pen[W * W];
    __shared__ float s_part[TPB / 64];

    const int tid = threadIdx.x;
    s_pen[tid] = penalty[tid];          // TPB == W*W == 256: one element each
    __syncthreads();

    const int gid   = blockIdx.x * TPB + tid;
    const int pos   = tid & 3;          // lane position within 4-lane row group
    const int cbase = pos << 2;         // first column this lane owns

    const float4* __restrict__ P4 = (const float4*)predict;
    const float4* __restrict__ T4 = (const float4*)target;

    float acc = 0.0f;

    for (int it = 0; it < NITER; it += UNROLL) {
        // Issue all coalesced loads first: 8 dwordx4 in flight per wave.
        float4 p[UNROLL], t[UNROLL];
#pragma unroll
        for (int u = 0; u < UNROLL; ++u) {
            const int f = gid + (it + u) * STRIDE;  // lane-contiguous float4 index
            p[u] = P4[f];
            t[u] = T4[f];
        }

#pragma unroll
        for (int u = 0; u < UNROLL; ++u) {
            const float pv0 = p[u].x, pv1 = p[u].y, pv2 = p[u].z, pv3 = p[u].w;

            // ---- argmax(predict) across the 4-lane row group ----
            float pm = pv0; int pi = cbase;
            if (pv1 > pm) { pm = pv1; pi = cbase + 1; }
            if (pv2 > pm) { pm = pv2; pi = cbase + 2; }
            if (pv3 > pm) { pm = pv3; pi = cbase + 3; }
            argmax_combine(pm, pi, __shfl_xor(pm, 1), __shfl_xor(pi, 1));
            argmax_combine(pm, pi, __shfl_xor(pm, 2), __shfl_xor(pi, 2));

            // ---- softmax denominator (numerator at argmax is exp(0)=1) ----
            float e = __expf(pv0 - pm) + __expf(pv1 - pm)
                    + __expf(pv2 - pm) + __expf(pv3 - pm);
            e += __shfl_xor(e, 1);
            e += __shfl_xor(e, 2);

            // ---- argmax(target) ----
            const float tv0 = t[u].x, tv1 = t[u].y, tv2 = t[u].z, tv3 = t[u].w;
            float tm = tv0; int ti = cbase;
            if (tv1 > tm) { tm = tv1; ti = cbase + 1; }
            if (tv2 > tm) { tm = tv2; ti = cbase + 2; }
            if (tv3 > tm) { tm = tv3; ti = cbase + 3; }
            argmax_combine(tm, ti, __shfl_xor(tm, 1), __shfl_xor(ti, 1));
            argmax_combine(tm, ti, __shfl_xor(tm, 2), __shfl_xor(ti, 2));

            // One lane per row accumulates w * softmax[pi] = w / e
            if (pos == 0) {
                const float w = (pi == ti) ? 0.0f : s_pen[ti * W + pi];
                acc += w / e;
            }
        }
    }

    // wave-64 reduction
#pragma unroll
    for (int off = 32; off > 0; off >>= 1)
        acc += __shfl_down(acc, off);

    const int lane = tid & 63;
    const int wid  = tid >> 6;
    if (lane == 0) s_part[wid] = acc;
    __syncthreads();

    if (tid == 0) {
        float tot = s_part[0] + s_part[1] + s_part[2] + s_part[3];
        atomicAdd(out, tot * (1.0f / (float)NROWS));
    }
}

extern "C" void kernel_launch(void* const* d_in, const int* in_sizes, int n_in,
                              void* d_out, int out_size, void* d_ws, size_t ws_size,
                              hipStream_t stream)
{
    const float* predict = (const float*)d_in[0];
    const float* target  = (const float*)d_in[1];
    const float* penalty = (const float*)d_in[2];
    float* out = (float*)d_out;

    // d_out is poisoned (0xAA) before every replay — zero it on-stream.
    hipMemsetAsync(out, 0, sizeof(float) * out_size, stream);

    dim3 grid(BLOCKS), block(TPB);
    cel_weight_kernel<<<grid, block, 0, stream>>>(predict, target, penalty, out);
}

// Round 3
// 279.520 us; speedup vs baseline: 1.0140x; 1.0140x over previous
//
#include <hip/hip_runtime.h>

#define NROWS 2097152
#define W 16
#define TPB 256
#define BLOCKS 4096
#define NTHREADS (BLOCKS * TPB)            // 1,048,576 threads
#define RPT (NROWS / NTHREADS)             // 2 rows per thread — exact, no tail

// Tree argmax over 16 values: depth-4 fmaxf tree + parallel equality mask.
// __ffs picks the FIRST matching index -> matches jnp.argmax tie-break.
__device__ __forceinline__ int argmax16(const float* v, float& mout)
{
    float a0 = fmaxf(v[0],  v[1]),  a1 = fmaxf(v[2],  v[3]);
    float a2 = fmaxf(v[4],  v[5]),  a3 = fmaxf(v[6],  v[7]);
    float a4 = fmaxf(v[8],  v[9]),  a5 = fmaxf(v[10], v[11]);
    float a6 = fmaxf(v[12], v[13]), a7 = fmaxf(v[14], v[15]);
    float b0 = fmaxf(a0, a1), b1 = fmaxf(a2, a3);
    float b2 = fmaxf(a4, a5), b3 = fmaxf(a6, a7);
    float m  = fmaxf(fmaxf(b0, b1), fmaxf(b2, b3));
    unsigned mask = 0u;
#pragma unroll
    for (int j = 0; j < 16; ++j) mask |= (v[j] == m) ? (1u << j) : 0u;
    mout = m;
    return __ffs(mask) - 1;
}

__global__ __launch_bounds__(TPB) void cel_weight_kernel(
    const float* __restrict__ predict,
    const float* __restrict__ target,
    const float* __restrict__ penalty,
    float* __restrict__ out)
{
    __shared__ float s_pen[W * W];
    __shared__ float s_part[TPB / 64];

    const int tid = threadIdx.x;
    s_pen[tid] = penalty[tid];          // TPB == 256 == W*W: one element each
    __syncthreads();

    const int gid = blockIdx.x * TPB + tid;

    // ---- Issue ALL 16 dwordx4 loads up front (16 KB in flight per wave).
    // Row 1's loads stay outstanding while row 0 computes (partial vmcnt).
    float4 pb[RPT][4], tb[RPT][4];
#pragma unroll
    for (int k = 0; k < RPT; ++k) {
        const float4* prow = (const float4*)predict + (size_t)(gid + k * NTHREADS) * 4;
        const float4* trow = (const float4*)target  + (size_t)(gid + k * NTHREADS) * 4;
        pb[k][0] = prow[0]; pb[k][1] = prow[1]; pb[k][2] = prow[2]; pb[k][3] = prow[3];
        tb[k][0] = trow[0]; tb[k][1] = trow[1]; tb[k][2] = trow[2]; tb[k][3] = trow[3];
    }

    float acc = 0.0f;

#pragma unroll
    for (int k = 0; k < RPT; ++k) {
        const float pv[W] = {pb[k][0].x, pb[k][0].y, pb[k][0].z, pb[k][0].w,
                             pb[k][1].x, pb[k][1].y, pb[k][1].z, pb[k][1].w,
                             pb[k][2].x, pb[k][2].y, pb[k][2].z, pb[k][2].w,
                             pb[k][3].x, pb[k][3].y, pb[k][3].z, pb[k][3].w};
        const float tv[W] = {tb[k][0].x, tb[k][0].y, tb[k][0].z, tb[k][0].w,
                             tb[k][1].x, tb[k][1].y, tb[k][1].z, tb[k][1].w,
                             tb[k][2].x, tb[k][2].y, tb[k][2].z, tb[k][2].w,
                             tb[k][3].x, tb[k][3].y, tb[k][3].z, tb[k][3].w};

        float pmax, tmax;
        const int pidx = argmax16(pv, pmax);
        const int tidx = argmax16(tv, tmax);

        // softmax denominator; numerator at argmax is exp(0)=1
        float s = 0.0f;
#pragma unroll
        for (int j = 0; j < W; ++j) s += __expf(pv[j] - pmax);

        const float w = s_pen[tidx * W + pidx];
        acc += (pidx == tidx) ? 0.0f : w / s;
    }

    // wave-64 reduction
#pragma unroll
    for (int off = 32; off > 0; off >>= 1)
        acc += __shfl_down(acc, off);

    const int lane = tid & 63;
    const int wid  = tid >> 6;
    if (lane == 0) s_part[wid] = acc;
    __syncthreads();

    if (tid == 0) {
        float tot = s_part[0] + s_part[1] + s_part[2] + s_part[3];
        atomicAdd(out, tot * (1.0f / (float)NROWS));
    }
}

extern "C" void kernel_launch(void* const* d_in, const int* in_sizes, int n_in,
                              void* d_out, int out_size, void* d_ws, size_t ws_size,
                              hipStream_t stream)
{
    const float* predict = (const float*)d_in[0];
    const float* target  = (const float*)d_in[1];
    const float* penalty = (const float*)d_in[2];
    float* out = (float*)d_out;

    // d_out is poisoned (0xAA) before every replay — zero it on-stream.
    hipMemsetAsync(out, 0, sizeof(float) * out_size, stream);

    dim3 grid(BLOCKS), block(TPB);
    cel_weight_kernel<<<grid, block, 0, stream>>>(predict, target, penalty, out);
}